// Round 1
// baseline (28224.771 us; speedup 1.0000x reference)
//
#include <hip/hip_runtime.h>
#include <hip/hip_bf16.h>
#include <hip/hip_cooperative_groups.h>
#include <math.h>

namespace cg = cooperative_groups;

// Problem constants
#define TT 128
#define BB 64
#define HH 512
#define VV 10000
#define TBm (TT*BB)      // 8192
#define H3 (3*HH)        // 1536
#define H2 (2*HH)        // 1024

typedef short bf16x8 __attribute__((ext_vector_type(8)));
typedef float f32x4 __attribute__((ext_vector_type(4)));
typedef __hip_bfloat16 bf16;

// ---------------- small utility kernels ----------------

__global__ void k_init_h(const float* __restrict__ hid, float* __restrict__ h0, float* __restrict__ h1) {
    int g = blockIdx.x * 256 + threadIdx.x;   // 2*BB*HH threads
    if (g < BB*HH) h0[g] = hid[g];
    else           h1[g - BB*HH] = hid[g];
}

// embedding gather -> f32 X (TB x E), row = t*B+b  (f32: feeds the recurrent chain)
__global__ void k_gather(const int* __restrict__ tok, const float* __restrict__ emb, float* __restrict__ X) {
    size_t g = (size_t)blockIdx.x * 256 + threadIdx.x;
    int row = (int)(g >> 9);
    int e   = (int)(g & 511);
    X[g] = emb[(size_t)tok[row] * HH + e];
}

// generic f32 -> bf16
__global__ void k_cvt(const float* __restrict__ in, bf16* __restrict__ out, int n) {
    int g = blockIdx.x * 256 + threadIdx.x;
    if (g < n) out[g] = __float2bfloat16(in[g]);
}

// A01[k][j] = sum_i fcW0[i][k] * Wx1[i][j]   (f32, feeds recurrent chain)
__global__ void k_a01(const float* __restrict__ fcW0, const float* __restrict__ Wx1, float* __restrict__ A01) {
    int j = blockIdx.x * 256 + threadIdx.x;   // 0..1535
    int k = blockIdx.y;                        // 0..511
    float a = 0.f;
    for (int i = 0; i < HH; i++) a = fmaf(fcW0[(size_t)i * HH + k], Wx1[(size_t)i * H3 + j], a);
    A01[(size_t)k * H3 + j] = a;
}

// b01[j] = sum_i fcb0[i]*Wx1[i][j] + b_rzh1[j]
__global__ void k_b01(const float* __restrict__ fcb0, const float* __restrict__ Wx1,
                      const float* __restrict__ brzh1, float* __restrict__ b01) {
    int j = blockIdx.x * 256 + threadIdx.x;
    float a = brzh1[j];
    for (int i = 0; i < HH; i++) a = fmaf(fcb0[i], Wx1[(size_t)i * H3 + j], a);
    b01[j] = a;
}

// ---------------- f32 GEMM: C[M,N] = A[M,K] @ W[K,N] + bias[N] ----------------
// Vector-ALU (no f32 MFMA on CDNA4). 64x64 tile, BK=16, 256 threads, 4x4/thread.
__global__ __launch_bounds__(256) void gemm_f32(const float* __restrict__ A,
                                                const float* __restrict__ W,
                                                const float* __restrict__ bias,
                                                float* __restrict__ C,
                                                int M, int N, int K) {
    __shared__ float As[16][68];   // As[k][m]
    __shared__ float Ws[16][68];   // Ws[k][n]
    const int tid = threadIdx.x;
    const int tx = tid & 15, ty = tid >> 4;
    const int m0 = blockIdx.y * 64, n0 = blockIdx.x * 64;
    float acc[4][4];
    for (int i = 0; i < 4; i++) for (int j = 0; j < 4; j++) acc[i][j] = 0.f;

    const int ar = tid >> 2, ac4 = (tid & 3) * 4;   // A-stage coords
    const int wk = tid >> 4, wc = (tid & 15) * 4;   // W-stage coords

    for (int kk = 0; kk < K; kk += 16) {
        float4 av = *(const float4*)&A[(size_t)(m0 + ar) * K + kk + ac4];
        As[ac4 + 0][ar] = av.x; As[ac4 + 1][ar] = av.y;
        As[ac4 + 2][ar] = av.z; As[ac4 + 3][ar] = av.w;
        *(float4*)&Ws[wk][wc] = *(const float4*)&W[(size_t)(kk + wk) * N + n0 + wc];
        __syncthreads();
        #pragma unroll
        for (int k = 0; k < 16; k++) {
            float4 a = *(const float4*)&As[k][ty * 4];
            float4 w = *(const float4*)&Ws[k][tx * 4];
            acc[0][0] = fmaf(a.x, w.x, acc[0][0]); acc[0][1] = fmaf(a.x, w.y, acc[0][1]);
            acc[0][2] = fmaf(a.x, w.z, acc[0][2]); acc[0][3] = fmaf(a.x, w.w, acc[0][3]);
            acc[1][0] = fmaf(a.y, w.x, acc[1][0]); acc[1][1] = fmaf(a.y, w.y, acc[1][1]);
            acc[1][2] = fmaf(a.y, w.z, acc[1][2]); acc[1][3] = fmaf(a.y, w.w, acc[1][3]);
            acc[2][0] = fmaf(a.z, w.x, acc[2][0]); acc[2][1] = fmaf(a.z, w.y, acc[2][1]);
            acc[2][2] = fmaf(a.z, w.z, acc[2][2]); acc[2][3] = fmaf(a.z, w.w, acc[2][3]);
            acc[3][0] = fmaf(a.w, w.x, acc[3][0]); acc[3][1] = fmaf(a.w, w.y, acc[3][1]);
            acc[3][2] = fmaf(a.w, w.z, acc[3][2]); acc[3][3] = fmaf(a.w, w.w, acc[3][3]);
        }
        __syncthreads();
    }
    for (int i = 0; i < 4; i++) {
        size_t row = (size_t)(m0 + ty * 4 + i) * N;
        for (int j = 0; j < 4; j++) {
            int col = n0 + tx * 4 + j;
            C[row + col] = acc[i][j] + bias[col];
        }
    }
}

// ---------------- bf16 MFMA GEMM: C[M,N] = A[M,K] @ B[N,K]^T + bias[N] ----------------
template<bool OUT_BF16>
__global__ __launch_bounds__(256) void gemm_bt(const ushort* __restrict__ A,
                                               const ushort* __restrict__ B,
                                               const float* __restrict__ bias,
                                               void* __restrict__ Cout,
                                               int M, int N, int K) {
    __shared__ ushort As[128 * 40];
    __shared__ ushort Bs[128 * 40];
    const int tid  = threadIdx.x;
    const int m0   = blockIdx.y * 128;
    const int n0   = blockIdx.x * 128;
    const int wave = tid >> 6, lane = tid & 63;
    const int wm   = (wave >> 1) * 64, wn = (wave & 1) * 64;
    const int l16  = lane & 15, quad = lane >> 4;

    f32x4 acc[4][4];
    {
        f32x4 zz = {0.f, 0.f, 0.f, 0.f};
        for (int i = 0; i < 4; i++) for (int j = 0; j < 4; j++) acc[i][j] = zz;
    }

    for (int kk = 0; kk < K; kk += 32) {
        for (int q = tid; q < 512; q += 256) {
            int r = q >> 2, c = (q & 3) * 8;
            *(bf16x8*)&As[r * 40 + c] = *(const bf16x8*)&A[(size_t)(m0 + r) * K + kk + c];
        }
        for (int q = tid; q < 512; q += 256) {
            int r = q >> 2, c = (q & 3) * 8;
            bf16x8 v; for (int i = 0; i < 8; i++) v[i] = 0;
            if (n0 + r < N) v = *(const bf16x8*)&B[(size_t)(n0 + r) * K + kk + c];
            *(bf16x8*)&Bs[r * 40 + c] = v;
        }
        __syncthreads();
        bf16x8 af[4], bg[4];
        for (int mi = 0; mi < 4; mi++) af[mi] = *(const bf16x8*)&As[(wm + mi * 16 + l16) * 40 + quad * 8];
        for (int ni = 0; ni < 4; ni++) bg[ni] = *(const bf16x8*)&Bs[(wn + ni * 16 + l16) * 40 + quad * 8];
        for (int mi = 0; mi < 4; mi++)
            for (int ni = 0; ni < 4; ni++)
                acc[mi][ni] = __builtin_amdgcn_mfma_f32_16x16x32_bf16(af[mi], bg[ni], acc[mi][ni], 0, 0, 0);
        __syncthreads();
    }

    for (int mi = 0; mi < 4; mi++)
        for (int ni = 0; ni < 4; ni++) {
            int col = n0 + wn + ni * 16 + l16;
            if (col < N) {
                float bs = bias[col];
                for (int r = 0; r < 4; r++) {
                    int row = m0 + wm + mi * 16 + quad * 4 + r;
                    float o = acc[mi][ni][r] + bs;
                    if (OUT_BF16) ((bf16*)Cout)[(size_t)row * N + col] = __float2bfloat16(o);
                    else          ((float*)Cout)[(size_t)row * N + col] = o;
                }
            }
        }
}

// ---------------- persistent cooperative recurrent kernel ----------------
// One launch replaces 512. Per step: 4 stages, each a set of 64x64xK64 GEMM chunks
// (4x4 register tile, A/W tiles in LDS) producing K-split f32 partials; the
// consuming stage finalizes gates while staging its A-tile. Weights are read
// ONCE per step (9 MB) instead of once per batch row (576 MB).

__device__ __forceinline__ float sigm_f(float x) { return 1.f / (1.f + __expf(-x)); }
__device__ __forceinline__ float tanh_f(float x) {
    float ax = fabsf(x);
    float e  = __expf(-2.f * ax);
    float t  = (1.f - e) / (1.f + e);
    return copysignf(t, x);
}
__device__ __forceinline__ float sum8(const float* __restrict__ p) {
    float4 a = *(const float4*)p;
    float4 b = *(const float4*)(p + 4);
    return ((a.x + a.y) + (a.z + a.w)) + ((b.x + b.y) + (b.z + b.w));
}

// W-tile: ws[k][j] = W[(kb+k)*N + jb+j], 64x64, rows padded to 68
__device__ __forceinline__ void stage_w64(float* __restrict__ ws, const float* __restrict__ W,
                                          int N, int kb, int jb, int tid) {
    int k = tid >> 2, jq = (tid & 3) << 4;
    const float4* s = (const float4*)(W + (size_t)(kb + k) * N + jb + jq);
    float4* d = (float4*)(ws + k * 68 + jq);
    d[0] = s[0]; d[1] = s[1]; d[2] = s[2]; d[3] = s[3];
}

// A-tile (transposed): hs[k][b] = H[b*512 + kb+k]
__device__ __forceinline__ void stage_a_plain(float* __restrict__ hs, const float* __restrict__ H,
                                              int kb, int tid) {
    int b = tid >> 2, ks = (tid & 3) << 4;
    const float4* s = (const float4*)(H + b * HH + kb + ks);
    float v[16];
    *(float4*)&v[0] = s[0]; *(float4*)&v[4] = s[1]; *(float4*)&v[8] = s[2]; *(float4*)&v[12] = s[3];
    #pragma unroll
    for (int i = 0; i < 16; i++) hs[(ks + i) * 68 + b] = v[i];
}

// rh0[b][k] = sigmoid(sum8 prz_r + GX0_r) * h0_prev
__device__ __forceinline__ void stage_a_rh0(float* __restrict__ hs, const float* __restrict__ prz,
                                            const float* __restrict__ GX0t, const float* __restrict__ h0r,
                                            int kb, int tid) {
    int b = tid >> 2, ks = (tid & 3) << 4;
    #pragma unroll 4
    for (int i = 0; i < 16; i++) {
        int k = kb + ks + i;
        float d = sum8(prz + ((b << 10) + k) * 8) + GX0t[b * H3 + k];
        hs[(ks + i) * 68 + b] = sigm_f(d) * h0r[b * HH + k];
    }
}

// h0'[b][k] = (1-z)h0 + z*tanh(sum8 pht0 + GX0_h); z from prz_z + GX0_z
__device__ __forceinline__ void stage_a_h0n(float* __restrict__ hs, const float* __restrict__ prz,
                                            const float* __restrict__ pht0, const float* __restrict__ GX0t,
                                            const float* __restrict__ h0r, float* __restrict__ h0w,
                                            int kb, int tid, bool wr) {
    int b = tid >> 2, ks = (tid & 3) << 4;
    #pragma unroll 4
    for (int i = 0; i < 16; i++) {
        int k = kb + ks + i;
        float z  = sigm_f(sum8(prz + ((b << 10) + HH + k) * 8) + GX0t[b * H3 + HH + k]);
        float ht = tanh_f(sum8(pht0 + ((b << 9) + k) * 8) + GX0t[b * H3 + 2 * HH + k]);
        float hp = h0r[b * HH + k];
        float hn = fmaf(z, ht - hp, hp);
        hs[(ks + i) * 68 + b] = hn;
        if (wr) h0w[b * HH + k] = hn;
    }
}

// rh1[b][k] = sigmoid(sum8 pg1_r + sum8 pgh1_r + b01_r) * h1_in
__device__ __forceinline__ void stage_a_rh1(float* __restrict__ hs, const float* __restrict__ pg1,
                                            const float* __restrict__ pgh1, const float* __restrict__ b01,
                                            const float* __restrict__ h1r, int kb, int tid) {
    int b = tid >> 2, ks = (tid & 3) << 4;
    #pragma unroll 4
    for (int i = 0; i < 16; i++) {
        int k = kb + ks + i;
        float d = sum8(pg1 + (b * H3 + k) * 8) + sum8(pgh1 + ((b << 10) + k) * 8) + b01[k];
        hs[(ks + i) * 68 + b] = sigm_f(d) * h1r[b * HH + k];
    }
}

// h1'[b][k] = (1-z1)h1 + z1*tanh(sum8 pht1 + sum8 pg1_h + b01_h)
__device__ __forceinline__ void stage_a_h1n(float* __restrict__ hs, const float* __restrict__ pg1,
                                            const float* __restrict__ pgh1, const float* __restrict__ pht1,
                                            const float* __restrict__ b01, const float* __restrict__ h1r,
                                            float* __restrict__ h1w, bf16* __restrict__ Hb,
                                            int kb, int tid, bool wr) {
    int b = tid >> 2, ks = (tid & 3) << 4;
    #pragma unroll 4
    for (int i = 0; i < 16; i++) {
        int k = kb + ks + i;
        float z  = sigm_f(sum8(pg1 + (b * H3 + HH + k) * 8) + sum8(pgh1 + ((b << 10) + HH + k) * 8) + b01[HH + k]);
        float ht = tanh_f(sum8(pht1 + ((b << 9) + k) * 8) + sum8(pg1 + (b * H3 + 2 * HH + k) * 8) + b01[2 * HH + k]);
        float hp = h1r[b * HH + k];
        float hn = fmaf(z, ht - hp, hp);
        if (hs) hs[(ks + i) * 68 + b] = hn;
        if (wr) { h1w[b * HH + k] = hn; Hb[b * HH + k] = __float2bfloat16(hn); }
    }
}

// 64x64 GEMM over K=64 (A,W tiles in LDS), store f32 partials kc-innermost
__device__ __forceinline__ void gemm_store(const float* __restrict__ hs, const float* __restrict__ ws,
                                           float* __restrict__ P, int N, int kc, int jb, int tid) {
    const int tx = tid & 15, ty = tid >> 4;
    float acc[4][4];
    #pragma unroll
    for (int i = 0; i < 4; i++)
        #pragma unroll
        for (int j = 0; j < 4; j++) acc[i][j] = 0.f;
    #pragma unroll 8
    for (int k = 0; k < 64; k++) {
        float4 a = *(const float4*)(hs + k * 68 + ty * 4);
        float4 w = *(const float4*)(ws + k * 68 + tx * 4);
        acc[0][0] = fmaf(a.x, w.x, acc[0][0]); acc[0][1] = fmaf(a.x, w.y, acc[0][1]);
        acc[0][2] = fmaf(a.x, w.z, acc[0][2]); acc[0][3] = fmaf(a.x, w.w, acc[0][3]);
        acc[1][0] = fmaf(a.y, w.x, acc[1][0]); acc[1][1] = fmaf(a.y, w.y, acc[1][1]);
        acc[1][2] = fmaf(a.y, w.z, acc[1][2]); acc[1][3] = fmaf(a.y, w.w, acc[1][3]);
        acc[2][0] = fmaf(a.z, w.x, acc[2][0]); acc[2][1] = fmaf(a.z, w.y, acc[2][1]);
        acc[2][2] = fmaf(a.z, w.z, acc[2][2]); acc[2][3] = fmaf(a.z, w.w, acc[2][3]);
        acc[3][0] = fmaf(a.w, w.x, acc[3][0]); acc[3][1] = fmaf(a.w, w.y, acc[3][1]);
        acc[3][2] = fmaf(a.w, w.z, acc[3][2]); acc[3][3] = fmaf(a.w, w.w, acc[3][3]);
    }
    #pragma unroll
    for (int i = 0; i < 4; i++) {
        int b = ty * 4 + i;
        #pragma unroll
        for (int j = 0; j < 4; j++) {
            int col = jb + tx * 4 + j;
            P[((size_t)(b * N + col) << 3) + kc] = acc[i][j];
        }
    }
}

struct RecArgs {
    const float *GX0, *Uh0, *Uh1, *Uht0, *Uht1, *A01, *b01;
    float *h0A, *h0B, *h1A, *h1B;
    float *prz, *pgh1A, *pgh1B, *pht0, *pg1, *pht1;
    bf16 *H1bf;
    float *hfin;
};

__global__ __launch_bounds__(256) void k_rec(RecArgs a) {
    cg::grid_group grid = cg::this_grid();
    __shared__ float hs[64 * 68];
    __shared__ float ws[64 * 68];
    const int tid = threadIdx.x;
    const int bid = blockIdx.x;

    for (int t = 0; t < TT; t++) {
        const float* GX0t = a.GX0 + (size_t)t * BB * H3;
        float* h0r   = (t & 1) ? a.h0B : a.h0A;          // h0 state input to step t
        float* h0w   = (t & 1) ? a.h0A : a.h0B;          // h0'(t) materialized here (S3)
        float* h1rS1 = ((t + 1) & 1) ? a.h1B : a.h1A;    // h1'(t-2) (input to h1'(t-1) combine)
        float* h1wS1 = (t & 1) ? a.h1B : a.h1A;          // h1'(t-1) materialized here (S1)
        float* h1rS4 = h1wS1;                            // h1 input to step t
        float* pgh1w = (t & 1) ? a.pgh1B : a.pgh1A;      // partials written this step
        float* pgh1r = (t & 1) ? a.pgh1A : a.pgh1B;      // partials from step t-1

        // ---- S1: 256 chunks: prz = h0@Uh0 ; pgh1 = h1@Uh1 (A = h1'(t-1) combine) ----
        for (int c = bid; c < 256; c += gridDim.x) {
            int g = c >> 7, kc = (c >> 4) & 7, jc = c & 15;
            int kb = kc << 6, jb = jc << 6;
            if (g == 0) {
                stage_a_plain(hs, h0r, kb, tid);
                stage_w64(ws, a.Uh0, H2, kb, jb, tid);
                __syncthreads();
                gemm_store(hs, ws, a.prz, H2, kc, jb, tid);
            } else {
                if (t == 0) stage_a_plain(hs, a.h1A, kb, tid);
                else stage_a_h1n(hs, a.pg1, pgh1r, a.pht1, a.b01, h1rS1, h1wS1,
                                 a.H1bf + (size_t)(t - 1) * BB * HH, kb, tid, jc == 0);
                stage_w64(ws, a.Uh1, H2, kb, jb, tid);
                __syncthreads();
                gemm_store(hs, ws, pgh1w, H2, kc, jb, tid);
            }
            __syncthreads();
        }
        grid.sync();

        // ---- S2: 64 chunks: pht0 = rh0 @ Uht0 ----
        for (int c = bid; c < 64; c += gridDim.x) {
            int kc = c >> 3, jc = c & 7;
            int kb = kc << 6, jb = jc << 6;
            stage_a_rh0(hs, a.prz, GX0t, h0r, kb, tid);
            stage_w64(ws, a.Uht0, HH, kb, jb, tid);
            __syncthreads();
            gemm_store(hs, ws, a.pht0, HH, kc, jb, tid);
            __syncthreads();
        }
        grid.sync();

        // ---- S3: 192 chunks: pg1 = h0' @ A01 (A = h0' combine; jc==0 writes h0w) ----
        for (int c = bid; c < 192; c += gridDim.x) {
            int kc = c / 24, jc = c % 24;
            int kb = kc << 6, jb = jc << 6;
            stage_a_h0n(hs, a.prz, a.pht0, GX0t, h0r, h0w, kb, tid, jc == 0);
            stage_w64(ws, a.A01, H3, kb, jb, tid);
            __syncthreads();
            gemm_store(hs, ws, a.pg1, H3, kc, jb, tid);
            __syncthreads();
        }
        grid.sync();

        // ---- S4: 64 chunks: pht1 = rh1 @ Uht1 ----
        for (int c = bid; c < 64; c += gridDim.x) {
            int kc = c >> 3, jc = c & 7;
            int kb = kc << 6, jb = jc << 6;
            stage_a_rh1(hs, a.pg1, pgh1w, a.b01, h1rS4, kb, tid);
            stage_w64(ws, a.Uht1, HH, kb, jb, tid);
            __syncthreads();
            gemm_store(hs, ws, a.pht1, HH, kc, jb, tid);
            __syncthreads();
        }
        grid.sync();
    }

    // ---- epilogue: finalize h1'(127) -> H1bf[127] + hfin[1]; copy h0 final -> hfin[0] ----
    {
        const float* pgh1r = a.pgh1B;   // written at S1(127) (t&1 = 1 -> B)
        const float* h1r   = a.h1B;     // h1'(126), materialized at S1(127)
        for (int c = bid; c < 16; c += gridDim.x) {
            int kb = (c & 7) << 6;
            if (c < 8) {
                stage_a_h1n(nullptr, a.pg1, pgh1r, a.pht1, a.b01, h1r,
                            a.hfin + BB * HH, a.H1bf + (size_t)127 * BB * HH, kb, tid, true);
            } else {
                int b = tid >> 2, ks = (tid & 3) << 4;
                const float4* s = (const float4*)(a.h0A + b * HH + kb + ks);  // t=127 odd -> h0w = h0A
                float4* d = (float4*)(a.hfin + b * HH + kb + ks);
                d[0] = s[0]; d[1] = s[1]; d[2] = s[2]; d[3] = s[3];
            }
        }
    }
}

// ---------------- launcher ----------------
extern "C" void kernel_launch(void* const* d_in, const int* in_sizes, int n_in,
                              void* d_out, int out_size, void* d_ws, size_t ws_size,
                              hipStream_t stream) {
    const int*   tok  = (const int*)d_in[0];
    const float* hid  = (const float*)d_in[1];
    const float* emb  = (const float*)d_in[2];
    const float* W_x  = (const float*)d_in[3];
    const float* U_h  = (const float*)d_in[4];
    const float* U_ht = (const float*)d_in[5];
    const float* brzh = (const float*)d_in[6];
    const float* fcW  = (const float*)d_in[7];
    const float* fcb  = (const float*)d_in[8];
    const float* decW = (const float*)d_in[9];
    const float* decb = (const float*)d_in[10];
    float* out = (float*)d_out;

    char* p = (char*)d_ws;
    auto carve = [&](size_t bytes) { char* r = p; p += (bytes + 255) & ~(size_t)255; return r; };
    float* GX0   = (float*)carve((size_t)TBm * H3 * 4);  // 50 MB (f32: feeds recurrence)
    float* Xf    = (float*)carve((size_t)TBm * HH * 4);  // 16.8 MB (X, then partials, then Inp2b)
    bf16* fcW1b  = (bf16*)carve((size_t)HH * HH * 2);
    bf16* decWb  = (bf16*)carve((size_t)VV * HH * 2);    // 10 MB
    bf16* H1bf   = (bf16*)carve((size_t)TBm * HH * 2);   // 8 MB
    float* A01   = (float*)carve((size_t)HH * H3 * 4);   // 3 MB
    float* b01   = (float*)carve((size_t)H3 * 4);
    float* h0A   = (float*)carve((size_t)BB * HH * 4);
    float* h0B   = (float*)carve((size_t)BB * HH * 4);
    float* h1A   = (float*)carve((size_t)BB * HH * 4);
    float* h1B   = (float*)carve((size_t)BB * HH * 4);

    // K-split partial buffers alias the Xf region (X consumed by gemm_f32 before k_rec;
    // Inp2b reuses it after k_rec). 11 MB < 16.8 MB.
    float* prz   = Xf;                                   // [64][1024][8] = 2 MB
    float* pgh1A = Xf + 1 * 524288;                      // 2 MB
    float* pgh1B = Xf + 2 * 524288;                      // 2 MB
    float* pht0  = Xf + 3 * 524288;                      // [64][512][8] = 1 MB
    float* pg1   = Xf + 3 * 524288 + 262144;             // [64][1536][8] = 3 MB
    float* pht1  = pg1 + 786432;                         // 1 MB
    bf16* Inp2b  = (bf16*)Xf;                            // decode-phase reuse

    const float* Uh0  = U_h;
    const float* Uh1  = U_h + (size_t)HH * H2;
    const float* Uht0 = U_ht;
    const float* Uht1 = U_ht + (size_t)HH * HH;
    const float* Wx1  = W_x + (size_t)HH * H3;

    // --- precompute phase (all parallel) ---
    k_init_h<<<256, 256, 0, stream>>>(hid, h0A, h1A);
    k_gather<<<(TBm * HH) / 256, 256, 0, stream>>>(tok, emb, Xf);
    k_cvt<<<(HH * HH + 255) / 256, 256, 0, stream>>>(fcW + (size_t)HH * HH, fcW1b, HH * HH);
    k_cvt<<<(VV * HH + 255) / 256, 256, 0, stream>>>(decW, decWb, VV * HH);
    k_a01<<<dim3(6, 512), 256, 0, stream>>>(fcW, Wx1, A01);
    k_b01<<<6, 256, 0, stream>>>(fcb, Wx1, brzh + H3, b01);
    // GX0 = X @ W_x0 + b_rzh0  (f32, natural (K,N) layout)
    gemm_f32<<<dim3(H3 / 64, TBm / 64), 256, 0, stream>>>(Xf, W_x, brzh, GX0, TBm, H3, HH);

    // --- sequential recurrent phase: ONE cooperative kernel, grid-wide syncs ---
    RecArgs ra;
    ra.GX0 = GX0; ra.Uh0 = Uh0; ra.Uh1 = Uh1; ra.Uht0 = Uht0; ra.Uht1 = Uht1;
    ra.A01 = A01; ra.b01 = b01;
    ra.h0A = h0A; ra.h0B = h0B; ra.h1A = h1A; ra.h1B = h1B;
    ra.prz = prz; ra.pgh1A = pgh1A; ra.pgh1B = pgh1B;
    ra.pht0 = pht0; ra.pg1 = pg1; ra.pht1 = pht1;
    ra.H1bf = H1bf; ra.hfin = out + (size_t)TBm * VV;
    void* kargs[] = { &ra };
    hipLaunchCooperativeKernel(k_rec, dim3(256), dim3(256), kargs, 0, stream);

    // --- decode phase (parallel big GEMMs, bf16 MFMA — no feedback) ---
    gemm_bt<true><<<dim3(HH / 128, TBm / 128), 256, 0, stream>>>(
        (const ushort*)H1bf, (const ushort*)fcW1b, fcb + HH, Inp2b, TBm, HH, HH);
    gemm_bt<false><<<dim3((VV + 127) / 128, TBm / 128), 256, 0, stream>>>(
        (const ushort*)Inp2b, (const ushort*)decWb, decb, out, TBm, VV, HH);
}

// Round 2
// 23593.727 us; speedup vs baseline: 1.1963x; 1.1963x over previous
//
#include <hip/hip_runtime.h>
#include <hip/hip_bf16.h>
#include <math.h>

// Problem constants
#define TT 128
#define BB 64
#define HH 512
#define VV 10000
#define TBm (TT*BB)      // 8192
#define H3 (3*HH)        // 1536
#define H2 (2*HH)        // 1024

#define NBLK 256         // persistent grid size (1 block/CU guaranteed co-resident)

typedef short bf16x8 __attribute__((ext_vector_type(8)));
typedef float f32x4 __attribute__((ext_vector_type(4)));
typedef __hip_bfloat16 bf16;

// ---------------- small utility kernels ----------------

__global__ void k_init_h(const float* __restrict__ hid, float* __restrict__ h0, float* __restrict__ h1,
                         unsigned* __restrict__ bar) {
    int g = blockIdx.x * 256 + threadIdx.x;   // 2*BB*HH threads
    if (g == 0) *bar = 0u;                    // zero the global barrier counter
    if (g < BB*HH) h0[g] = hid[g];
    else           h1[g - BB*HH] = hid[g];
}

// embedding gather -> f32 X (TB x E), row = t*B+b  (f32: feeds the recurrent chain)
__global__ void k_gather(const int* __restrict__ tok, const float* __restrict__ emb, float* __restrict__ X) {
    size_t g = (size_t)blockIdx.x * 256 + threadIdx.x;
    int row = (int)(g >> 9);
    int e   = (int)(g & 511);
    X[g] = emb[(size_t)tok[row] * HH + e];
}

// generic f32 -> bf16
__global__ void k_cvt(const float* __restrict__ in, bf16* __restrict__ out, int n) {
    int g = blockIdx.x * 256 + threadIdx.x;
    if (g < n) out[g] = __float2bfloat16(in[g]);
}

// A01[k][j] = sum_i fcW0[i][k] * Wx1[i][j]   (f32, feeds recurrent chain)
__global__ void k_a01(const float* __restrict__ fcW0, const float* __restrict__ Wx1, float* __restrict__ A01) {
    int j = blockIdx.x * 256 + threadIdx.x;   // 0..1535
    int k = blockIdx.y;                        // 0..511
    float a = 0.f;
    for (int i = 0; i < HH; i++) a = fmaf(fcW0[(size_t)i * HH + k], Wx1[(size_t)i * H3 + j], a);
    A01[(size_t)k * H3 + j] = a;
}

// b01[j] = sum_i fcb0[i]*Wx1[i][j] + b_rzh1[j]
__global__ void k_b01(const float* __restrict__ fcb0, const float* __restrict__ Wx1,
                      const float* __restrict__ brzh1, float* __restrict__ b01) {
    int j = blockIdx.x * 256 + threadIdx.x;
    float a = brzh1[j];
    for (int i = 0; i < HH; i++) a = fmaf(fcb0[i], Wx1[(size_t)i * H3 + j], a);
    b01[j] = a;
}

// ---------------- f32 GEMM: C[M,N] = A[M,K] @ W[K,N] + bias[N] ----------------
__global__ __launch_bounds__(256) void gemm_f32(const float* __restrict__ A,
                                                const float* __restrict__ W,
                                                const float* __restrict__ bias,
                                                float* __restrict__ C,
                                                int M, int N, int K) {
    __shared__ float As[16][68];   // As[k][m]
    __shared__ float Ws[16][68];   // Ws[k][n]
    const int tid = threadIdx.x;
    const int tx = tid & 15, ty = tid >> 4;
    const int m0 = blockIdx.y * 64, n0 = blockIdx.x * 64;
    float acc[4][4];
    for (int i = 0; i < 4; i++) for (int j = 0; j < 4; j++) acc[i][j] = 0.f;

    const int ar = tid >> 2, ac4 = (tid & 3) * 4;   // A-stage coords
    const int wk = tid >> 4, wc = (tid & 15) * 4;   // W-stage coords

    for (int kk = 0; kk < K; kk += 16) {
        float4 av = *(const float4*)&A[(size_t)(m0 + ar) * K + kk + ac4];
        As[ac4 + 0][ar] = av.x; As[ac4 + 1][ar] = av.y;
        As[ac4 + 2][ar] = av.z; As[ac4 + 3][ar] = av.w;
        *(float4*)&Ws[wk][wc] = *(const float4*)&W[(size_t)(kk + wk) * N + n0 + wc];
        __syncthreads();
        #pragma unroll
        for (int k = 0; k < 16; k++) {
            float4 a = *(const float4*)&As[k][ty * 4];
            float4 w = *(const float4*)&Ws[k][tx * 4];
            acc[0][0] = fmaf(a.x, w.x, acc[0][0]); acc[0][1] = fmaf(a.x, w.y, acc[0][1]);
            acc[0][2] = fmaf(a.x, w.z, acc[0][2]); acc[0][3] = fmaf(a.x, w.w, acc[0][3]);
            acc[1][0] = fmaf(a.y, w.x, acc[1][0]); acc[1][1] = fmaf(a.y, w.y, acc[1][1]);
            acc[1][2] = fmaf(a.y, w.z, acc[1][2]); acc[1][3] = fmaf(a.y, w.w, acc[1][3]);
            acc[2][0] = fmaf(a.z, w.x, acc[2][0]); acc[2][1] = fmaf(a.z, w.y, acc[2][1]);
            acc[2][2] = fmaf(a.z, w.z, acc[2][2]); acc[2][3] = fmaf(a.z, w.w, acc[2][3]);
            acc[3][0] = fmaf(a.w, w.x, acc[3][0]); acc[3][1] = fmaf(a.w, w.y, acc[3][1]);
            acc[3][2] = fmaf(a.w, w.z, acc[3][2]); acc[3][3] = fmaf(a.w, w.w, acc[3][3]);
        }
        __syncthreads();
    }
    for (int i = 0; i < 4; i++) {
        size_t row = (size_t)(m0 + ty * 4 + i) * N;
        for (int j = 0; j < 4; j++) {
            int col = n0 + tx * 4 + j;
            C[row + col] = acc[i][j] + bias[col];
        }
    }
}

// ---------------- bf16 MFMA GEMM: C[M,N] = A[M,K] @ B[N,K]^T + bias[N] ----------------
template<bool OUT_BF16>
__global__ __launch_bounds__(256) void gemm_bt(const ushort* __restrict__ A,
                                               const ushort* __restrict__ B,
                                               const float* __restrict__ bias,
                                               void* __restrict__ Cout,
                                               int M, int N, int K) {
    __shared__ ushort As[128 * 40];
    __shared__ ushort Bs[128 * 40];
    const int tid  = threadIdx.x;
    const int m0   = blockIdx.y * 128;
    const int n0   = blockIdx.x * 128;
    const int wave = tid >> 6, lane = tid & 63;
    const int wm   = (wave >> 1) * 64, wn = (wave & 1) * 64;
    const int l16  = lane & 15, quad = lane >> 4;

    f32x4 acc[4][4];
    {
        f32x4 zz = {0.f, 0.f, 0.f, 0.f};
        for (int i = 0; i < 4; i++) for (int j = 0; j < 4; j++) acc[i][j] = zz;
    }

    for (int kk = 0; kk < K; kk += 32) {
        for (int q = tid; q < 512; q += 256) {
            int r = q >> 2, c = (q & 3) * 8;
            *(bf16x8*)&As[r * 40 + c] = *(const bf16x8*)&A[(size_t)(m0 + r) * K + kk + c];
        }
        for (int q = tid; q < 512; q += 256) {
            int r = q >> 2, c = (q & 3) * 8;
            bf16x8 v; for (int i = 0; i < 8; i++) v[i] = 0;
            if (n0 + r < N) v = *(const bf16x8*)&B[(size_t)(n0 + r) * K + kk + c];
            *(bf16x8*)&Bs[r * 40 + c] = v;
        }
        __syncthreads();
        bf16x8 af[4], bg[4];
        for (int mi = 0; mi < 4; mi++) af[mi] = *(const bf16x8*)&As[(wm + mi * 16 + l16) * 40 + quad * 8];
        for (int ni = 0; ni < 4; ni++) bg[ni] = *(const bf16x8*)&Bs[(wn + ni * 16 + l16) * 40 + quad * 8];
        for (int mi = 0; mi < 4; mi++)
            for (int ni = 0; ni < 4; ni++)
                acc[mi][ni] = __builtin_amdgcn_mfma_f32_16x16x32_bf16(af[mi], bg[ni], acc[mi][ni], 0, 0, 0);
        __syncthreads();
    }

    for (int mi = 0; mi < 4; mi++)
        for (int ni = 0; ni < 4; ni++) {
            int col = n0 + wn + ni * 16 + l16;
            if (col < N) {
                float bs = bias[col];
                for (int r = 0; r < 4; r++) {
                    int row = m0 + wm + mi * 16 + quad * 4 + r;
                    float o = acc[mi][ni][r] + bs;
                    if (OUT_BF16) ((bf16*)Cout)[(size_t)row * N + col] = __float2bfloat16(o);
                    else          ((float*)Cout)[(size_t)row * N + col] = o;
                }
            }
        }
}

// ---------------- persistent recurrent kernel (hand-rolled grid barrier) ----------------
// cg::grid_group::sync() measured ~54us/sync (sleep-based polling) -> replaced with a
// monotonic-counter barrier: release-RMW arrive (emits waitcnt+wbl2 for cross-XCD
// visibility), tight relaxed agent-scope spin (sc1 load, reads Infinity Cache),
// one agent acquire fence per block on exit.

__device__ __forceinline__ void gbar(unsigned* __restrict__ cnt, unsigned& target) {
    __syncthreads();
    if (threadIdx.x == 0) {
        target += NBLK;
        __hip_atomic_fetch_add(cnt, 1u, __ATOMIC_RELEASE, __HIP_MEMORY_SCOPE_AGENT);
        while (__hip_atomic_load(cnt, __ATOMIC_RELAXED, __HIP_MEMORY_SCOPE_AGENT) < target) {}
        __threadfence();   // agent acquire: invalidate stale L1/L2 before partial reads
    }
    __syncthreads();
}

__device__ __forceinline__ float sigm_f(float x) { return 1.f / (1.f + __expf(-x)); }
__device__ __forceinline__ float tanh_f(float x) {
    float ax = fabsf(x);
    float e  = __expf(-2.f * ax);
    float t  = (1.f - e) / (1.f + e);
    return copysignf(t, x);
}
__device__ __forceinline__ float sum8(const float* __restrict__ p) {
    float4 a = *(const float4*)p;
    float4 b = *(const float4*)(p + 4);
    return ((a.x + a.y) + (a.z + a.w)) + ((b.x + b.y) + (b.z + b.w));
}

// W-tile: ws[k][j] = W[(kb+k)*N + jb+j], 64x64, rows padded to 68
__device__ __forceinline__ void stage_w64(float* __restrict__ ws, const float* __restrict__ W,
                                          int N, int kb, int jb, int tid) {
    int k = tid >> 2, jq = (tid & 3) << 4;
    const float4* s = (const float4*)(W + (size_t)(kb + k) * N + jb + jq);
    float4* d = (float4*)(ws + k * 68 + jq);
    d[0] = s[0]; d[1] = s[1]; d[2] = s[2]; d[3] = s[3];
}

// A-tile (transposed): hs[k][b] = H[b*512 + kb+k]
__device__ __forceinline__ void stage_a_plain(float* __restrict__ hs, const float* __restrict__ H,
                                              int kb, int tid) {
    int b = tid >> 2, ks = (tid & 3) << 4;
    const float4* s = (const float4*)(H + b * HH + kb + ks);
    float v[16];
    *(float4*)&v[0] = s[0]; *(float4*)&v[4] = s[1]; *(float4*)&v[8] = s[2]; *(float4*)&v[12] = s[3];
    #pragma unroll
    for (int i = 0; i < 16; i++) hs[(ks + i) * 68 + b] = v[i];
}

// rh0[b][k] = sigmoid(sum8 prz_r + GX0_r) * h0_prev
__device__ __forceinline__ void stage_a_rh0(float* __restrict__ hs, const float* __restrict__ prz,
                                            const float* __restrict__ GX0t, const float* __restrict__ h0r,
                                            int kb, int tid) {
    int b = tid >> 2, ks = (tid & 3) << 4;
    #pragma unroll 4
    for (int i = 0; i < 16; i++) {
        int k = kb + ks + i;
        float d = sum8(prz + ((b << 10) + k) * 8) + GX0t[b * H3 + k];
        hs[(ks + i) * 68 + b] = sigm_f(d) * h0r[b * HH + k];
    }
}

// h0'[b][k] = (1-z)h0 + z*tanh(sum8 pht0 + GX0_h); z from prz_z + GX0_z
__device__ __forceinline__ void stage_a_h0n(float* __restrict__ hs, const float* __restrict__ prz,
                                            const float* __restrict__ pht0, const float* __restrict__ GX0t,
                                            const float* __restrict__ h0r, float* __restrict__ h0w,
                                            int kb, int tid, bool wr) {
    int b = tid >> 2, ks = (tid & 3) << 4;
    #pragma unroll 4
    for (int i = 0; i < 16; i++) {
        int k = kb + ks + i;
        float z  = sigm_f(sum8(prz + ((b << 10) + HH + k) * 8) + GX0t[b * H3 + HH + k]);
        float ht = tanh_f(sum8(pht0 + ((b << 9) + k) * 8) + GX0t[b * H3 + 2 * HH + k]);
        float hp = h0r[b * HH + k];
        float hn = fmaf(z, ht - hp, hp);
        hs[(ks + i) * 68 + b] = hn;
        if (wr) h0w[b * HH + k] = hn;
    }
}

// rh1[b][k] = sigmoid(sum8 pg1_r + sum8 pgh1_r + b01_r) * h1_in
__device__ __forceinline__ void stage_a_rh1(float* __restrict__ hs, const float* __restrict__ pg1,
                                            const float* __restrict__ pgh1, const float* __restrict__ b01,
                                            const float* __restrict__ h1r, int kb, int tid) {
    int b = tid >> 2, ks = (tid & 3) << 4;
    #pragma unroll 4
    for (int i = 0; i < 16; i++) {
        int k = kb + ks + i;
        float d = sum8(pg1 + (b * H3 + k) * 8) + sum8(pgh1 + ((b << 10) + k) * 8) + b01[k];
        hs[(ks + i) * 68 + b] = sigm_f(d) * h1r[b * HH + k];
    }
}

// h1'[b][k] = (1-z1)h1 + z1*tanh(sum8 pht1 + sum8 pg1_h + b01_h)
__device__ __forceinline__ void stage_a_h1n(float* __restrict__ hs, const float* __restrict__ pg1,
                                            const float* __restrict__ pgh1, const float* __restrict__ pht1,
                                            const float* __restrict__ b01, const float* __restrict__ h1r,
                                            float* __restrict__ h1w, bf16* __restrict__ Hb,
                                            int kb, int tid, bool wr) {
    int b = tid >> 2, ks = (tid & 3) << 4;
    #pragma unroll 4
    for (int i = 0; i < 16; i++) {
        int k = kb + ks + i;
        float z  = sigm_f(sum8(pg1 + (b * H3 + HH + k) * 8) + sum8(pgh1 + ((b << 10) + HH + k) * 8) + b01[HH + k]);
        float ht = tanh_f(sum8(pht1 + ((b << 9) + k) * 8) + sum8(pg1 + (b * H3 + 2 * HH + k) * 8) + b01[2 * HH + k]);
        float hp = h1r[b * HH + k];
        float hn = fmaf(z, ht - hp, hp);
        if (hs) hs[(ks + i) * 68 + b] = hn;
        if (wr) { h1w[b * HH + k] = hn; Hb[b * HH + k] = __float2bfloat16(hn); }
    }
}

// 64x64 GEMM over K=64 (A,W tiles in LDS), store f32 partials kc-innermost
__device__ __forceinline__ void gemm_store(const float* __restrict__ hs, const float* __restrict__ ws,
                                           float* __restrict__ P, int N, int kc, int jb, int tid) {
    const int tx = tid & 15, ty = tid >> 4;
    float acc[4][4];
    #pragma unroll
    for (int i = 0; i < 4; i++)
        #pragma unroll
        for (int j = 0; j < 4; j++) acc[i][j] = 0.f;
    #pragma unroll 8
    for (int k = 0; k < 64; k++) {
        float4 a = *(const float4*)(hs + k * 68 + ty * 4);
        float4 w = *(const float4*)(ws + k * 68 + tx * 4);
        acc[0][0] = fmaf(a.x, w.x, acc[0][0]); acc[0][1] = fmaf(a.x, w.y, acc[0][1]);
        acc[0][2] = fmaf(a.x, w.z, acc[0][2]); acc[0][3] = fmaf(a.x, w.w, acc[0][3]);
        acc[1][0] = fmaf(a.y, w.x, acc[1][0]); acc[1][1] = fmaf(a.y, w.y, acc[1][1]);
        acc[1][2] = fmaf(a.y, w.z, acc[1][2]); acc[1][3] = fmaf(a.y, w.w, acc[1][3]);
        acc[2][0] = fmaf(a.z, w.x, acc[2][0]); acc[2][1] = fmaf(a.z, w.y, acc[2][1]);
        acc[2][2] = fmaf(a.z, w.z, acc[2][2]); acc[2][3] = fmaf(a.z, w.w, acc[2][3]);
        acc[3][0] = fmaf(a.w, w.x, acc[3][0]); acc[3][1] = fmaf(a.w, w.y, acc[3][1]);
        acc[3][2] = fmaf(a.w, w.z, acc[3][2]); acc[3][3] = fmaf(a.w, w.w, acc[3][3]);
    }
    #pragma unroll
    for (int i = 0; i < 4; i++) {
        int b = ty * 4 + i;
        #pragma unroll
        for (int j = 0; j < 4; j++) {
            int col = jb + tx * 4 + j;
            P[((size_t)(b * N + col) << 3) + kc] = acc[i][j];
        }
    }
}

struct RecArgs {
    const float *GX0, *Uh0, *Uh1, *Uht0, *Uht1, *A01, *b01;
    float *h0A, *h0B, *h1A, *h1B;
    float *prz, *pgh1A, *pgh1B, *pht0, *pg1, *pht1;
    bf16 *H1bf;
    float *hfin;
    unsigned *bar;
};

__global__ __launch_bounds__(256) void k_rec(RecArgs a) {
    __shared__ float hs[64 * 68];
    __shared__ float ws[64 * 68];
    const int tid = threadIdx.x;
    const int bid = blockIdx.x;
    unsigned bar_target = 0;

    for (int t = 0; t < TT; t++) {
        const float* GX0t = a.GX0 + (size_t)t * BB * H3;
        float* h0r   = (t & 1) ? a.h0B : a.h0A;          // h0 state input to step t
        float* h0w   = (t & 1) ? a.h0A : a.h0B;          // h0'(t) materialized here (S3)
        float* h1rS1 = ((t + 1) & 1) ? a.h1B : a.h1A;    // h1'(t-2) (input to h1'(t-1) combine)
        float* h1wS1 = (t & 1) ? a.h1B : a.h1A;          // h1'(t-1) materialized here (S1)
        float* h1rS4 = h1wS1;                            // h1 input to step t
        float* pgh1w = (t & 1) ? a.pgh1B : a.pgh1A;      // partials written this step
        float* pgh1r = (t & 1) ? a.pgh1A : a.pgh1B;      // partials from step t-1

        // ---- S1: 256 chunks: prz = h0@Uh0 ; pgh1 = h1@Uh1 (A = h1'(t-1) combine) ----
        for (int c = bid; c < 256; c += NBLK) {
            int g = c >> 7, kc = (c >> 4) & 7, jc = c & 15;
            int kb = kc << 6, jb = jc << 6;
            if (g == 0) {
                stage_a_plain(hs, h0r, kb, tid);
                stage_w64(ws, a.Uh0, H2, kb, jb, tid);
                __syncthreads();
                gemm_store(hs, ws, a.prz, H2, kc, jb, tid);
            } else {
                if (t == 0) stage_a_plain(hs, a.h1A, kb, tid);
                else stage_a_h1n(hs, a.pg1, pgh1r, a.pht1, a.b01, h1rS1, h1wS1,
                                 a.H1bf + (size_t)(t - 1) * BB * HH, kb, tid, jc == 0);
                stage_w64(ws, a.Uh1, H2, kb, jb, tid);
                __syncthreads();
                gemm_store(hs, ws, pgh1w, H2, kc, jb, tid);
            }
            __syncthreads();
        }
        gbar(a.bar, bar_target);

        // ---- S2: 64 chunks: pht0 = rh0 @ Uht0 ----
        for (int c = bid; c < 64; c += NBLK) {
            int kc = c >> 3, jc = c & 7;
            int kb = kc << 6, jb = jc << 6;
            stage_a_rh0(hs, a.prz, GX0t, h0r, kb, tid);
            stage_w64(ws, a.Uht0, HH, kb, jb, tid);
            __syncthreads();
            gemm_store(hs, ws, a.pht0, HH, kc, jb, tid);
            __syncthreads();
        }
        gbar(a.bar, bar_target);

        // ---- S3: 192 chunks: pg1 = h0' @ A01 (A = h0' combine; jc==0 writes h0w) ----
        for (int c = bid; c < 192; c += NBLK) {
            int kc = c / 24, jc = c % 24;
            int kb = kc << 6, jb = jc << 6;
            stage_a_h0n(hs, a.prz, a.pht0, GX0t, h0r, h0w, kb, tid, jc == 0);
            stage_w64(ws, a.A01, H3, kb, jb, tid);
            __syncthreads();
            gemm_store(hs, ws, a.pg1, H3, kc, jb, tid);
            __syncthreads();
        }
        gbar(a.bar, bar_target);

        // ---- S4: 64 chunks: pht1 = rh1 @ Uht1 ----
        for (int c = bid; c < 64; c += NBLK) {
            int kc = c >> 3, jc = c & 7;
            int kb = kc << 6, jb = jc << 6;
            stage_a_rh1(hs, a.pg1, pgh1w, a.b01, h1rS4, kb, tid);
            stage_w64(ws, a.Uht1, HH, kb, jb, tid);
            __syncthreads();
            gemm_store(hs, ws, a.pht1, HH, kc, jb, tid);
            __syncthreads();
        }
        gbar(a.bar, bar_target);
    }

    // ---- epilogue: finalize h1'(127) -> H1bf[127] + hfin[1]; copy h0 final -> hfin[0] ----
    {
        const float* pgh1r = a.pgh1B;   // written at S1(127) (t&1 = 1 -> B)
        const float* h1r   = a.h1B;     // h1'(126), materialized at S1(127)
        for (int c = bid; c < 16; c += NBLK) {
            int kb = (c & 7) << 6;
            if (c < 8) {
                stage_a_h1n(nullptr, a.pg1, pgh1r, a.pht1, a.b01, h1r,
                            a.hfin + BB * HH, a.H1bf + (size_t)127 * BB * HH, kb, tid, true);
            } else {
                int b = tid >> 2, ks = (tid & 3) << 4;
                const float4* s = (const float4*)(a.h0A + b * HH + kb + ks);  // t=127 odd -> h0w = h0A
                float4* d = (float4*)(a.hfin + b * HH + kb + ks);
                d[0] = s[0]; d[1] = s[1]; d[2] = s[2]; d[3] = s[3];
            }
        }
    }
}

// ---------------- launcher ----------------
extern "C" void kernel_launch(void* const* d_in, const int* in_sizes, int n_in,
                              void* d_out, int out_size, void* d_ws, size_t ws_size,
                              hipStream_t stream) {
    const int*   tok  = (const int*)d_in[0];
    const float* hid  = (const float*)d_in[1];
    const float* emb  = (const float*)d_in[2];
    const float* W_x  = (const float*)d_in[3];
    const float* U_h  = (const float*)d_in[4];
    const float* U_ht = (const float*)d_in[5];
    const float* brzh = (const float*)d_in[6];
    const float* fcW  = (const float*)d_in[7];
    const float* fcb  = (const float*)d_in[8];
    const float* decW = (const float*)d_in[9];
    const float* decb = (const float*)d_in[10];
    float* out = (float*)d_out;

    char* p = (char*)d_ws;
    auto carve = [&](size_t bytes) { char* r = p; p += (bytes + 255) & ~(size_t)255; return r; };
    float* GX0   = (float*)carve((size_t)TBm * H3 * 4);  // 50 MB (f32: feeds recurrence)
    float* Xf    = (float*)carve((size_t)TBm * HH * 4);  // 16.8 MB (X, then partials, then Inp2b)
    bf16* fcW1b  = (bf16*)carve((size_t)HH * HH * 2);
    bf16* decWb  = (bf16*)carve((size_t)VV * HH * 2);    // 10 MB
    bf16* H1bf   = (bf16*)carve((size_t)TBm * HH * 2);   // 8 MB
    float* A01   = (float*)carve((size_t)HH * H3 * 4);   // 3 MB
    float* b01   = (float*)carve((size_t)H3 * 4);
    float* h0A   = (float*)carve((size_t)BB * HH * 4);
    float* h0B   = (float*)carve((size_t)BB * HH * 4);
    float* h1A   = (float*)carve((size_t)BB * HH * 4);
    float* h1B   = (float*)carve((size_t)BB * HH * 4);
    unsigned* bar = (unsigned*)carve(256);

    // K-split partial buffers alias the Xf region (X consumed by gemm_f32 before k_rec;
    // Inp2b reuses it after k_rec). 11 MB < 16.8 MB.
    float* prz   = Xf;                                   // [64][1024][8] = 2 MB
    float* pgh1A = Xf + 1 * 524288;                      // 2 MB
    float* pgh1B = Xf + 2 * 524288;                      // 2 MB
    float* pht0  = Xf + 3 * 524288;                      // [64][512][8] = 1 MB
    float* pg1   = Xf + 3 * 524288 + 262144;             // [64][1536][8] = 3 MB
    float* pht1  = pg1 + 786432;                         // 1 MB
    bf16* Inp2b  = (bf16*)Xf;                            // decode-phase reuse

    const float* Uh0  = U_h;
    const float* Uh1  = U_h + (size_t)HH * H2;
    const float* Uht0 = U_ht;
    const float* Uht1 = U_ht + (size_t)HH * HH;
    const float* Wx1  = W_x + (size_t)HH * H3;

    // --- precompute phase (all parallel) ---
    k_init_h<<<256, 256, 0, stream>>>(hid, h0A, h1A, bar);
    k_gather<<<(TBm * HH) / 256, 256, 0, stream>>>(tok, emb, Xf);
    k_cvt<<<(HH * HH + 255) / 256, 256, 0, stream>>>(fcW + (size_t)HH * HH, fcW1b, HH * HH);
    k_cvt<<<(VV * HH + 255) / 256, 256, 0, stream>>>(decW, decWb, VV * HH);
    k_a01<<<dim3(6, 512), 256, 0, stream>>>(fcW, Wx1, A01);
    k_b01<<<6, 256, 0, stream>>>(fcb, Wx1, brzh + H3, b01);
    // GX0 = X @ W_x0 + b_rzh0  (f32, natural (K,N) layout)
    gemm_f32<<<dim3(H3 / 64, TBm / 64), 256, 0, stream>>>(Xf, W_x, brzh, GX0, TBm, H3, HH);

    // --- sequential recurrent phase: ONE persistent kernel, hand-rolled grid barriers ---
    RecArgs ra;
    ra.GX0 = GX0; ra.Uh0 = Uh0; ra.Uh1 = Uh1; ra.Uht0 = Uht0; ra.Uht1 = Uht1;
    ra.A01 = A01; ra.b01 = b01;
    ra.h0A = h0A; ra.h0B = h0B; ra.h1A = h1A; ra.h1B = h1B;
    ra.prz = prz; ra.pgh1A = pgh1A; ra.pgh1B = pgh1B;
    ra.pht0 = pht0; ra.pg1 = pg1; ra.pht1 = pht1;
    ra.H1bf = H1bf; ra.hfin = out + (size_t)TBm * VV;
    ra.bar = bar;
    void* kargs[] = { &ra };
    hipLaunchCooperativeKernel(k_rec, dim3(NBLK), dim3(256), kargs, 0, stream);

    // --- decode phase (parallel big GEMMs, bf16 MFMA — no feedback) ---
    gemm_bt<true><<<dim3(HH / 128, TBm / 128), 256, 0, stream>>>(
        (const ushort*)H1bf, (const ushort*)fcW1b, fcb + HH, Inp2b, TBm, HH, HH);
    gemm_bt<false><<<dim3((VV + 127) / 128, TBm / 128), 256, 0, stream>>>(
        (const ushort*)Inp2b, (const ushort*)decWb, decb, out, TBm, VV, HH);
}